// Round 9
// baseline (189.079 us; speedup 1.0000x reference)
//
#include <hip/hip_runtime.h>
#include <hip/hip_bf16.h>
#include <cstdint>
#include <cstddef>

// SetConvDecoder on MI355X (gfx950).
// out[b,t,c] = (1/128) * sum_g exp(-0.5*||(xt[b,t]-xg[b,g])/ls||^2) * zg[b,g,c]
// B=4, NT=2048, NG=16384, DZ=128, DX=2.
//
// Round-9: kill the convoy. R5/R8 fit: 435 cyc/iter fixed barrier+vmcnt
// overhead + ~3x-issue dependency stalls (2-phase structural ceiling).
// New main: NO LDS, NO vmcnt asm, register double-buffered direct global
// loads (B-frags + triplets), compiler-scheduled waits. 4 waves/block share
// one B-stream via L1; bare s_barrier every 4 tiles only for L1 alignment.
// 512 blocks (b4 x mtg16 x ksp8) x 256 thr; 32-row waves; partials+reduce
// epilogue (no atomics) as in R5/R7.

typedef float  f32x4  __attribute__((ext_vector_type(4)));
typedef float  f32x16 __attribute__((ext_vector_type(16)));
typedef short  short8 __attribute__((ext_vector_type(8)));
typedef unsigned short ushort4v __attribute__((ext_vector_type(4)));
typedef unsigned short ushort8 __attribute__((ext_vector_type(8)));

#if __has_builtin(__builtin_amdgcn_exp2f)
#define EXP2F(x) __builtin_amdgcn_exp2f(x)
#else
#define EXP2F(x) exp2f(x)
#endif

#define AS1C(p) ((const __attribute__((address_space(1))) void*)(p))
#define AS3(p)  ((__attribute__((address_space(3))) void*)(p))

__device__ __forceinline__ unsigned short bf16_bits(float f) {
  __bf16 h = (__bf16)f;
  return __builtin_bit_cast(unsigned short, h);
}

// ---------------------------------------------------------------------------
// Pre-kernel: 1024 blocks (b4 x 256 groups of 64 g) x 256 threads.
// zg -> bf16*(1/128) in per-16k-tile fragment layout via LDS transpose.
// xg triplets now TILED + lane-contiguous: per 16k-tile 192 B =
//   [q2:2][slot:8][3 floats], slot = hi*4+j for k16 = 4*q2 + 8*hi + j,
// so a consuming lane reads its 24 floats as 6 contiguous dwordx4.
// xt: (u0,u1,-|u|^2,0) 16B/row.  u = x * sqrt(0.5*log2 e) / ls.
// ---------------------------------------------------------------------------
__global__ __launch_bounds__(256) void pre_kernel(
    const float* __restrict__ x_grid, const float* __restrict__ z_grid,
    const float* __restrict__ xt, const float* __restrict__ lsp,
    unsigned short* __restrict__ zgb, float* __restrict__ xg_trip,
    float* __restrict__ xt4)
{
  __shared__ unsigned short lt[64 * 128];   // 16 KB row-major [row][c]
  const int bid = blockIdx.x;
  const int b   = bid >> 8;
  const int grp = bid & 255;
  const int tid = threadIdx.x;
  const size_t gbase = (size_t)b * 16384 + grp * 64;
  const float sc = 1.0f / 128.0f;

  const float* zr = z_grid + gbase * 128;
  #pragma unroll
  for (int it = 0; it < 8; ++it) {
    const int idx = it * 256 + tid;
    const int row = idx >> 5, c4 = idx & 31;
    f32x4 v = *(const f32x4*)(zr + row * 128 + c4 * 4);
    ushort4v o;
    o.x = bf16_bits(v.x * sc); o.y = bf16_bits(v.y * sc);
    o.z = bf16_bits(v.z * sc); o.w = bf16_bits(v.w * sc);
    *(ushort4v*)(lt + row * 128 + c4 * 4) = o;
  }

  if (tid < 128) {
    const float ls0 = 1e-5f + log1pf(expf(lsp[0]));
    const float ls1 = 1e-5f + log1pf(expf(lsp[1]));
    const float cs  = sqrtf(0.7213475204444817f);   // sqrt(0.5*log2 e)
    const float s0 = cs / ls0, s1 = cs / ls1;
    if (tid < 64) {
      const size_t g = gbase + tid;
      const float u0 = x_grid[g * 2 + 0] * s0;
      const float u1 = x_grid[g * 2 + 1] * s1;
      const int gk = grp * 64 + tid;          // k index within b
      const int tile = gk >> 4, k16 = gk & 15;
      const int jj = k16 & 3, qq = (k16 >> 2) & 1, hh = k16 >> 3;
      float* d = xg_trip + ((size_t)(b * 1024 + tile)) * 48
               + qq * 24 + (hh * 4 + jj) * 3;
      d[0] = 2.0f * u0; d[1] = 2.0f * u1; d[2] = -(u0 * u0 + u1 * u1);
    } else if (bid < 128) {
      const int bx = bid >> 5;
      const int r  = (bid & 31) * 64 + (tid - 64);
      const float u0 = xt[((size_t)(bx * 2048 + r)) * 2 + 0] * s0;
      const float u1 = xt[((size_t)(bx * 2048 + r)) * 2 + 1] * s1;
      f32x4 d; d.x = u0; d.y = u1; d.z = -(u0 * u0 + u1 * u1); d.w = 0.0f;
      *(f32x4*)(xt4 + ((size_t)(bx * 2048 + r)) * 4) = d;
    }
  }

  __syncthreads();

  const int q2p = tid >> 7, c = tid & 127;
  #pragma unroll
  for (int h = 0; h < 4; ++h) {            // 4 16-k tiles per block
    ushort8 o;
    #pragma unroll
    for (int hi = 0; hi < 2; ++hi)
      #pragma unroll
      for (int j = 0; j < 4; ++j)
        o[hi * 4 + j] = lt[(h * 16 + 4 * q2p + 8 * hi + j) * 128 + c];
    *(ushort8*)(zgb + ((size_t)(b * 1024 + grp * 4 + h)) * 2048
                    + (size_t)(q2p * 128 + c) * 8) = o;
  }
}

// ---------------------------------------------------------------------------
// Main kernel: 512 blocks (b4 x mtg16 x ksp8, XCD-swizzled) x 256 thr =
// 4 free-running waves of 32 rows each. No LDS. Register double-buffer.
// ---------------------------------------------------------------------------
#define LOADT(s, F, T)                                                   \
  {                                                                      \
    const char* zp_ = zsrc + (size_t)(s) * 4096;                         \
    F[0] = *(const short8*)(zp_ + 0);                                    \
    F[1] = *(const short8*)(zp_ + 512);                                  \
    F[2] = *(const short8*)(zp_ + 1024);                                 \
    F[3] = *(const short8*)(zp_ + 1536);                                 \
    const char* tp_ = tsrc + (size_t)(s) * 192;                          \
    T[0] = *(const f32x4*)(tp_ + 0);  T[1] = *(const f32x4*)(tp_ + 16);  \
    T[2] = *(const f32x4*)(tp_ + 32); T[3] = *(const f32x4*)(tp_ + 48);  \
    T[4] = *(const f32x4*)(tp_ + 64); T[5] = *(const f32x4*)(tp_ + 80);  \
  }

#define COMPUTE(F, T)                                                    \
  {                                                                      \
    const float* f_ = (const float*)&(T)[0];                             \
    union { short8 s8; __bf16 e[8]; } u_;                                \
    _Pragma("unroll")                                                    \
    for (int j2 = 0; j2 < 8; ++j2) {                                     \
      float arg_ = __builtin_fmaf(at0, f_[3 * j2],                       \
                   __builtin_fmaf(at1, f_[3 * j2 + 1],                   \
                                  ca + f_[3 * j2 + 2]));                 \
      u_.e[j2] = (__bf16)EXP2F(arg_);                                    \
    }                                                                    \
    acc[0] = __builtin_amdgcn_mfma_f32_32x32x16_bf16(u_.s8, F[0], acc[0], 0, 0, 0); \
    acc[1] = __builtin_amdgcn_mfma_f32_32x32x16_bf16(u_.s8, F[1], acc[1], 0, 0, 0); \
    acc[2] = __builtin_amdgcn_mfma_f32_32x32x16_bf16(u_.s8, F[2], acc[2], 0, 0, 0); \
    acc[3] = __builtin_amdgcn_mfma_f32_32x32x16_bf16(u_.s8, F[3], acc[3], 0, 0, 0); \
  }

__global__ __launch_bounds__(256, 2) void main_kernel(
    const unsigned short* __restrict__ zgb,
    const float* __restrict__ xg_trip,
    const float* __restrict__ xt4,
    float* __restrict__ out,
    float* __restrict__ partials)     // nullptr -> atomic fallback
{
  const int raw = blockIdx.x;
  const int lid = (raw & 7) * 64 + (raw >> 3);    // bijective XCD swizzle
  const int mtg = lid & 15;
  const int b   = (lid >> 4) & 3;
  const int ksp = lid >> 6;                       // 0..7

  const int tid = threadIdx.x;
  const int w   = tid >> 6;           // wave: 32-row sub-tile
  const int l   = tid & 63;
  const int l31 = l & 31;
  const int q2  = l >> 5;

  // xt triplet for this lane's row (constant over the loop)
  const int r = mtg * 128 + w * 32 + l31;
  f32x4 tv = *(const f32x4*)(xt4 + ((size_t)(b * 2048 + r)) * 4);
  const float at0 = tv.x, at1 = tv.y, ca = tv.z;

  f32x16 acc[4];
  #pragma unroll
  for (int ni = 0; ni < 4; ++ni)
    #pragma unroll
    for (int e = 0; e < 16; ++e)
      acc[ni][e] = 0.0f;

  // per-lane stream bases (same across the block's 4 waves -> L1 reuse)
  const char* zsrc = (const char*)zgb
                   + ((size_t)(b * 1024 + ksp * 128)) * 4096
                   + q2 * 2048 + l31 * 16;
  const char* tsrc = (const char*)xg_trip
                   + ((size_t)(b * 1024 + ksp * 128)) * 192
                   + q2 * 96;

  short8 F0[4], F1[4];
  f32x4  T0[6], T1[6];

  LOADT(0, F0, T0);

  for (int sb = 0; sb < 32; ++sb) {   // 128 tiles, groups of 4
    __builtin_amdgcn_s_barrier();     // bare alignment barrier (L1 locality)
    #pragma unroll
    for (int u = 0; u < 4; ++u) {
      const int s  = sb * 4 + u;
      const int nx = (s + 1 < 128) ? s + 1 : s;
      if (u & 1) { LOADT(nx, F0, T0); COMPUTE(F1, T1); }
      else       { LOADT(nx, F1, T1); COMPUTE(F0, T0); }
    }
  }

  // epilogue: plain coalesced partial stores (zg pre-scaled by 1/128)
  if (partials) {
    float* pb = partials + (size_t)ksp * 1048576
              + ((size_t)(b * 2048 + mtg * 128 + w * 32)) * 128;
    #pragma unroll
    for (int ni = 0; ni < 4; ++ni)
      #pragma unroll
      for (int rr = 0; rr < 16; ++rr) {
        const int row = (rr & 3) + 8 * (rr >> 2) + 4 * q2;  // verified C/D map
        pb[row * 128 + ni * 32 + l31] = acc[ni][rr];
      }
  } else {
    #pragma unroll
    for (int ni = 0; ni < 4; ++ni)
      #pragma unroll
      for (int rr = 0; rr < 16; ++rr) {
        const int row = mtg * 128 + w * 32 + (rr & 3) + 8 * (rr >> 2) + 4 * q2;
        atomicAdd(out + ((size_t)b * 2048 + row) * 128 + ni * 32 + l31,
                  acc[ni][rr]);
      }
  }
}

// ---------------------------------------------------------------------------
// Reduce: out = sum over 8 ksp partial slices (zg pre-scaled by 1/128).
// ---------------------------------------------------------------------------
__global__ __launch_bounds__(256) void reduce_kernel(
    const float* __restrict__ partials, float* __restrict__ out)
{
  const size_t base = ((size_t)blockIdx.x * 256 + threadIdx.x) * 4;
  const float* p = partials + base;
  f32x4 s = *(const f32x4*)p;
  #pragma unroll
  for (int ksv = 1; ksv < 8; ++ksv) {
    f32x4 v = *(const f32x4*)(p + (size_t)ksv * 1048576);
    s.x += v.x; s.y += v.y; s.z += v.z; s.w += v.w;
  }
  *(f32x4*)(out + base) = s;
}

// ---------------------------------------------------------------------------
extern "C" void kernel_launch(void* const* d_in, const int* in_sizes, int n_in,
                              void* d_out, int out_size, void* d_ws, size_t ws_size,
                              hipStream_t stream) {
  const float* x_grid = (const float*)d_in[0];   // (4,128,128,2)
  const float* z_grid = (const float*)d_in[1];   // (4,128,128,128)
  const float* xt     = (const float*)d_in[2];   // (4,2048,2)
  const float* lsp    = (const float*)d_in[3];   // (2,)
  float* out = (float*)d_out;                    // (4,2048,128) f32

  char* ws = (char*)d_ws;
  unsigned short* zgb = (unsigned short*)ws;                   // 16 MB
  float* xg_trip = (float*)(ws + 16777216);                    // 768 KB
  float* xt4     = (float*)(ws + 16777216 + 786432);           // 128 KB
  const size_t poff = 16777216 + 786432 + 131072;              // 17694720
  const bool use_partials = ws_size >= poff + 33554432;        // +32 MB
  float* partials = use_partials ? (float*)(ws + poff) : nullptr;

  if (!use_partials)
    hipMemsetAsync(d_out, 0, (size_t)out_size * sizeof(float), stream);
  pre_kernel<<<1024, 256, 0, stream>>>(x_grid, z_grid, xt, lsp,
                                       zgb, xg_trip, xt4);
  main_kernel<<<512, 256, 0, stream>>>(zgb, xg_trip, xt4, out, partials);
  if (use_partials)
    reduce_kernel<<<1024, 256, 0, stream>>>(partials, out);
}

// Round 10
// 144.300 us; speedup vs baseline: 1.3103x; 1.3103x over previous
//
#include <hip/hip_runtime.h>
#include <hip/hip_bf16.h>
#include <cstdint>
#include <cstddef>

// SetConvDecoder on MI355X (gfx950).
// out[b,t,c] = (1/128) * sum_g exp(-0.5*||(xt[b,t]-xg[b,g])/ls||^2) * zg[b,g,c]
// B=4, NT=2048, NG=16384, DZ=128, DX=2.
//
// Round-10 (delta from R5, the best measured structure @57us main):
//  1. BK=32: 32 iterations (2 sub-tiles each) -> half the barrier convoys.
//  2. xg-triplets: global->register ping-pong (TA/TB), NOT via LDS ->
//     LDS read pipe 10 -> 4 ds_read_b128 per iter per wave.
//     FIFO-counted vmcnt(4) waits exactly {stage(s), loadT(s)}, leaves
//     stage(s+1) in flight.
//  3. Ring-4 x 16KB slots (64KB), stage-ahead 2. Epilogue kk-exchange in
//     two 32KB mi-rounds. Partials (8 slices) + reduce kernel, no atomics.

typedef float  f32x4  __attribute__((ext_vector_type(4)));
typedef float  f32x16 __attribute__((ext_vector_type(16)));
typedef short  short8 __attribute__((ext_vector_type(8)));
typedef unsigned short ushort4v __attribute__((ext_vector_type(4)));
typedef unsigned short ushort8 __attribute__((ext_vector_type(8)));

#if __has_builtin(__builtin_amdgcn_exp2f)
#define EXP2F(x) __builtin_amdgcn_exp2f(x)
#else
#define EXP2F(x) exp2f(x)
#endif

#define AS1C(p) ((const __attribute__((address_space(1))) void*)(p))
#define AS3(p)  ((__attribute__((address_space(3))) void*)(p))

__device__ __forceinline__ unsigned short bf16_bits(float f) {
  __bf16 h = (__bf16)f;
  return __builtin_bit_cast(unsigned short, h);
}

// ---------------------------------------------------------------------------
// Pre-kernel (R5 verbatim): 1024 blocks (b4 x 256 groups of 64 g) x 256 thr.
// zg -> bf16*(1/128) in per-16k-tile fragment layout via LDS transpose;
// xg triplets (2u0,2u1,-|u|^2) 12B/g g-major; xt (u0,u1,-|u|^2,0) 16B/row.
// ---------------------------------------------------------------------------
__global__ __launch_bounds__(256) void pre_kernel(
    const float* __restrict__ x_grid, const float* __restrict__ z_grid,
    const float* __restrict__ xt, const float* __restrict__ lsp,
    unsigned short* __restrict__ zgb, float* __restrict__ xg_trip,
    float* __restrict__ xt4)
{
  __shared__ unsigned short lt[64 * 128];   // 16 KB row-major [row][c]
  const int bid = blockIdx.x;
  const int b   = bid >> 8;
  const int grp = bid & 255;
  const int tid = threadIdx.x;
  const size_t gbase = (size_t)b * 16384 + grp * 64;
  const float sc = 1.0f / 128.0f;

  const float* zr = z_grid + gbase * 128;
  #pragma unroll
  for (int it = 0; it < 8; ++it) {
    const int idx = it * 256 + tid;
    const int row = idx >> 5, c4 = idx & 31;
    f32x4 v = *(const f32x4*)(zr + row * 128 + c4 * 4);
    ushort4v o;
    o.x = bf16_bits(v.x * sc); o.y = bf16_bits(v.y * sc);
    o.z = bf16_bits(v.z * sc); o.w = bf16_bits(v.w * sc);
    *(ushort4v*)(lt + row * 128 + c4 * 4) = o;
  }

  if (tid < 128) {
    const float ls0 = 1e-5f + log1pf(expf(lsp[0]));
    const float ls1 = 1e-5f + log1pf(expf(lsp[1]));
    const float cs  = sqrtf(0.7213475204444817f);   // sqrt(0.5*log2 e)
    const float s0 = cs / ls0, s1 = cs / ls1;
    if (tid < 64) {
      const size_t g = gbase + tid;
      const float u0 = x_grid[g * 2 + 0] * s0;
      const float u1 = x_grid[g * 2 + 1] * s1;
      float* d = xg_trip + g * 3;
      d[0] = 2.0f * u0; d[1] = 2.0f * u1; d[2] = -(u0 * u0 + u1 * u1);
    } else if (bid < 128) {
      const int bx = bid >> 5;
      const int r  = (bid & 31) * 64 + (tid - 64);
      const float u0 = xt[((size_t)(bx * 2048 + r)) * 2 + 0] * s0;
      const float u1 = xt[((size_t)(bx * 2048 + r)) * 2 + 1] * s1;
      f32x4 d; d.x = u0; d.y = u1; d.z = -(u0 * u0 + u1 * u1); d.w = 0.0f;
      *(f32x4*)(xt4 + ((size_t)(bx * 2048 + r)) * 4) = d;
    }
  }

  __syncthreads();

  const int q2p = tid >> 7, c = tid & 127;
  #pragma unroll
  for (int h = 0; h < 4; ++h) {            // 4 16-k tiles per block
    ushort8 o;
    #pragma unroll
    for (int hi = 0; hi < 2; ++hi)
      #pragma unroll
      for (int j = 0; j < 4; ++j)
        o[hi * 4 + j] = lt[(h * 16 + 4 * q2p + 8 * hi + j) * 128 + c];
    *(ushort8*)(zgb + ((size_t)(b * 1024 + grp * 4 + h)) * 2048
                    + (size_t)(q2p * 128 + c) * 8) = o;
  }
}

// ---------------------------------------------------------------------------
// Main kernel: 512 blocks (b4 x mt16 x ksp8, XCD-swizzled) x 256 thr =
// 4 waves (rh2 x kk2). Ring-4 x [kk2][sub2][rh2 x 2KB] = 64 KB.
// ---------------------------------------------------------------------------
__global__ __launch_bounds__(256, 2) void main_kernel(
    const unsigned short* __restrict__ zgb,
    const float* __restrict__ xg_trip,
    const float* __restrict__ xt4,
    float* __restrict__ out,
    float* __restrict__ partials)     // nullptr -> atomic fallback
{
  __shared__ __align__(128) char smem[65536];

  const int raw = blockIdx.x;
  const int lid = (raw & 7) * 64 + (raw >> 3);    // bijective XCD swizzle
  const int mt  = lid & 15;
  const int b   = (lid >> 4) & 3;
  const int ksp = lid >> 6;                       // 0..7

  const int tid = threadIdx.x;
  const int wv  = tid >> 6;
  const int l   = tid & 63;
  const int rh  = wv & 1;             // row half (64 rows)
  const int kk  = wv >> 1;            // in-block k-split
  const int l31 = l & 31;
  const int q2  = l >> 5;
  const int chunk = ksp * 2 + kk;     // 16 chunks of 64 16k-tiles

  float at0[2], at1[2], ca[2];
  #pragma unroll
  for (int mi = 0; mi < 2; ++mi) {
    const int r = mt * 128 + rh * 64 + mi * 32 + l31;
    f32x4 v = *(const f32x4*)(xt4 + ((size_t)(b * 2048 + r)) * 4);
    at0[mi] = v.x; at1[mi] = v.y; ca[mi] = v.z;
  }

  f32x16 acc[2][4];
  #pragma unroll
  for (int mi = 0; mi < 2; ++mi)
    #pragma unroll
    for (int ni = 0; ni < 4; ++ni)
      #pragma unroll
      for (int e = 0; e < 16; ++e)
        acc[mi][ni][e] = 0.0f;

  const char* zsrc = (const char*)zgb + ((size_t)(b * 1024 + chunk * 64)) * 4096;
  // per-lane triplet base (q2-group reads its own 48B slices)
  const char* tsrc = (const char*)xg_trip
                   + ((size_t)(b * 16384 + chunk * 1024)) * 12 + q2 * 48;

  auto stage = [&](int s) {           // 4 gl_lds: rh-half of sub-tiles 2s,2s+1
    const char* zs = zsrc + (size_t)s * 8192 + rh * 2048;
    char* zd = smem + (s & 3) * 16384 + kk * 8192 + rh * 2048;
    __builtin_amdgcn_global_load_lds(AS1C(zs + l * 16), AS3(zd + l * 16), 16, 0, 0);
    __builtin_amdgcn_global_load_lds(AS1C(zs + 1024 + l * 16),
                                     AS3(zd + 1024 + l * 16), 16, 0, 0);
    __builtin_amdgcn_global_load_lds(AS1C(zs + 4096 + l * 16),
                                     AS3(zd + 4096 + l * 16), 16, 0, 0);
    __builtin_amdgcn_global_load_lds(AS1C(zs + 5120 + l * 16),
                                     AS3(zd + 5120 + l * 16), 16, 0, 0);
  };

  auto loadT = [&](int s, f32x4* T) { // 6 dwordx4 (both sub-tiles' 24 floats)
    const char* tp = tsrc + (size_t)s * 384;
    T[0]  = *(const f32x4*)(tp + 0);
    T[1]  = *(const f32x4*)(tp + 16);
    T[2]  = *(const f32x4*)(tp + 32);
    T[3]  = *(const f32x4*)(tp + 96);
    T[4]  = *(const f32x4*)(tp + 112);
    T[5]  = *(const f32x4*)(tp + 128);
    T[6]  = *(const f32x4*)(tp + 192);
    T[7]  = *(const f32x4*)(tp + 208);
    T[8]  = *(const f32x4*)(tp + 224);
    T[9]  = *(const f32x4*)(tp + 288);
    T[10] = *(const f32x4*)(tp + 304);
    T[11] = *(const f32x4*)(tp + 320);
  };

  auto computeIter = [&](int s, const f32x4* T) {
    #pragma unroll
    for (int sub = 0; sub < 2; ++sub) {
      const f32x4 L0 = T[sub * 6 + 0], L1 = T[sub * 6 + 1], L2 = T[sub * 6 + 2];
      const f32x4 H0 = T[sub * 6 + 3], H1 = T[sub * 6 + 4], H2 = T[sub * 6 + 5];
      float g0[8], g1[8], cb[8];
      g0[0]=L0.x; g1[0]=L0.y; cb[0]=L0.z;
      g0[1]=L0.w; g1[1]=L1.x; cb[1]=L1.y;
      g0[2]=L1.z; g1[2]=L1.w; cb[2]=L2.x;
      g0[3]=L2.y; g1[3]=L2.z; cb[3]=L2.w;
      g0[4]=H0.x; g1[4]=H0.y; cb[4]=H0.z;
      g0[5]=H0.w; g1[5]=H1.x; cb[5]=H1.y;
      g0[6]=H1.z; g1[6]=H1.w; cb[6]=H2.x;
      g0[7]=H2.y; g1[7]=H2.z; cb[7]=H2.w;

      const char* zt = smem + (s & 3) * 16384 + kk * 8192 + sub * 4096
                     + q2 * 2048 + l31 * 16;
      short8 bfr[4];
      #pragma unroll
      for (int ni = 0; ni < 4; ++ni)
        bfr[ni] = *(const short8*)(zt + ni * 512);

      short8 af[2];
      #pragma unroll
      for (int mi = 0; mi < 2; ++mi) {
        union { short8 s8; __bf16 e[8]; } u;
        #pragma unroll
        for (int j = 0; j < 8; ++j) {
          float arg = __builtin_fmaf(at0[mi], g0[j],
                      __builtin_fmaf(at1[mi], g1[j], ca[mi] + cb[j]));
          u.e[j] = (__bf16)EXP2F(arg);
        }
        af[mi] = u.s8;
      }

      #pragma unroll
      for (int mi = 0; mi < 2; ++mi)
        #pragma unroll
        for (int ni = 0; ni < 4; ++ni)
          acc[mi][ni] = __builtin_amdgcn_mfma_f32_32x32x16_bf16(
              af[mi], bfr[ni], acc[mi][ni], 0, 0, 0);
    }
  };

  f32x4 TA[12], TB[12];
  // prologue mirrors steady-state FIFO: stage(s), loadT(s), stage(s+1)
  stage(0); loadT(0, TA); stage(1);

  for (int i = 0; i < 16; ++i) {
    { const int s = 2 * i;            // s <= 30
      // FIFO: [stage(s), loadT(s), stage(s+1)] -> leave newest 4
      asm volatile("s_waitcnt vmcnt(4)" ::: "memory");
      __builtin_amdgcn_s_barrier();
      asm volatile("" ::: "memory");
      loadT(s + 1, TB);               // s+1 <= 31, always valid
      if (s + 2 < 32) stage(s + 2);   // slot (s+2)&3: last read at iter s-2
      computeIter(s, TA);
    }
    { const int s = 2 * i + 1;
      if (s < 31) { asm volatile("s_waitcnt vmcnt(4)" ::: "memory"); }
      else        { asm volatile("s_waitcnt vmcnt(0)" ::: "memory"); }
      __builtin_amdgcn_s_barrier();
      asm volatile("" ::: "memory");
      if (s + 1 < 32) loadT(s + 1, TA);
      if (s + 2 < 32) stage(s + 2);
      computeIter(s, TB);
    }
  }

  // ---- in-block kk reduction: two 32KB mi-rounds in smem ----
  __syncthreads();                    // loop reads done; reuse smem
  float* red = (float*)smem;
  float* pb = partials ? partials + ((size_t)(ksp * 64 + b * 16 + mt)) * 16384
                       : nullptr;
  #pragma unroll
  for (int mi = 0; mi < 2; ++mi) {
    if (kk == 1) {
      #pragma unroll
      for (int ni = 0; ni < 4; ++ni)
        #pragma unroll
        for (int q = 0; q < 4; ++q) {
          f32x4 v;
          v.x = acc[mi][ni][q * 4 + 0]; v.y = acc[mi][ni][q * 4 + 1];
          v.z = acc[mi][ni][q * 4 + 2]; v.w = acc[mi][ni][q * 4 + 3];
          *(f32x4*)(red + rh * 4096 + ni * 1024 + q * 256 + l * 4) = v;
        }
    }
    __syncthreads();
    if (kk == 0) {
      #pragma unroll
      for (int ni = 0; ni < 4; ++ni) {
        #pragma unroll
        for (int q = 0; q < 4; ++q) {
          f32x4 v = *(const f32x4*)(red + rh * 4096 + ni * 1024 + q * 256 + l * 4);
          acc[mi][ni][q * 4 + 0] += v.x; acc[mi][ni][q * 4 + 1] += v.y;
          acc[mi][ni][q * 4 + 2] += v.z; acc[mi][ni][q * 4 + 3] += v.w;
        }
        #pragma unroll
        for (int r = 0; r < 16; ++r) {
          const int row = rh * 64 + mi * 32
                        + (r & 3) + 8 * (r >> 2) + 4 * q2;  // verified C/D map
          const int col = ni * 32 + l31;
          if (pb) {
            pb[row * 128 + col] = acc[mi][ni][r];           // plain store
          } else {
            atomicAdd(out + ((size_t)b * 2048 + mt * 128 + row) * 128 + col,
                      acc[mi][ni][r]);
          }
        }
      }
    }
    __syncthreads();
  }
}

// ---------------------------------------------------------------------------
// Reduce: out = sum over 8 ksp partial slices (zg pre-scaled by 1/128).
// ---------------------------------------------------------------------------
__global__ __launch_bounds__(256) void reduce_kernel(
    const float* __restrict__ partials, float* __restrict__ out)
{
  const size_t base = ((size_t)blockIdx.x * 256 + threadIdx.x) * 4;
  const float* p = partials + base;
  f32x4 s = *(const f32x4*)p;
  #pragma unroll
  for (int ksv = 1; ksv < 8; ++ksv) {
    f32x4 v = *(const f32x4*)(p + (size_t)ksv * 1048576);
    s.x += v.x; s.y += v.y; s.z += v.z; s.w += v.w;
  }
  *(f32x4*)(out + base) = s;
}

// ---------------------------------------------------------------------------
extern "C" void kernel_launch(void* const* d_in, const int* in_sizes, int n_in,
                              void* d_out, int out_size, void* d_ws, size_t ws_size,
                              hipStream_t stream) {
  const float* x_grid = (const float*)d_in[0];   // (4,128,128,2)
  const float* z_grid = (const float*)d_in[1];   // (4,128,128,128)
  const float* xt     = (const float*)d_in[2];   // (4,2048,2)
  const float* lsp    = (const float*)d_in[3];   // (2,)
  float* out = (float*)d_out;                    // (4,2048,128) f32

  char* ws = (char*)d_ws;
  unsigned short* zgb = (unsigned short*)ws;                   // 16 MB
  float* xg_trip = (float*)(ws + 16777216);                    // 768 KB
  float* xt4     = (float*)(ws + 16777216 + 786432);           // 128 KB
  const size_t poff = 16777216 + 786432 + 131072;              // 17694720
  const bool use_partials = ws_size >= poff + 33554432;        // +32 MB
  float* partials = use_partials ? (float*)(ws + poff) : nullptr;

  if (!use_partials)
    hipMemsetAsync(d_out, 0, (size_t)out_size * sizeof(float), stream);
  pre_kernel<<<1024, 256, 0, stream>>>(x_grid, z_grid, xt, lsp,
                                       zgb, xg_trip, xt4);
  main_kernel<<<512, 256, 0, stream>>>(zgb, xg_trip, xt4, out, partials);
  if (use_partials)
    reduce_kernel<<<1024, 256, 0, stream>>>(partials, out);
}